// Round 5
// baseline (899.407 us; speedup 1.0000x reference)
//
#include <hip/hip_runtime.h>
#include <math.h>

typedef __bf16 bf16x8 __attribute__((ext_vector_type(8)));
typedef __bf16 bf16x4 __attribute__((ext_vector_type(4)));
typedef float  floatx4 __attribute__((ext_vector_type(4)));

#define AS1(p) ((__attribute__((address_space(1))) void*)(p))
#define AS3(p) ((__attribute__((address_space(3))) void*)(p))

#define MASKV (-1.0e30f)
#define SOFTMAX_SCALE_LOG2 0.1803368801111244f   // 0.125 * log2(e)

// ---------------------------------------------------------------------------
// fp32 -> bf16 conversion, 4 elems/thread, fully coalesced.
// ---------------------------------------------------------------------------
__global__ __launch_bounds__(256)
void cvt_kernel(const float* __restrict__ in, __bf16* __restrict__ out)
{
    const int i = (blockIdx.x * 256 + threadIdx.x) * 4;
    const floatx4 v = *(const floatx4*)(in + i);
    bf16x4 o;
    o[0] = (__bf16)v[0]; o[1] = (__bf16)v[1];
    o[2] = (__bf16)v[2]; o[3] = (__bf16)v[3];
    *(bf16x4*)(out + i) = o;
}

// ---------------------------------------------------------------------------
// C[M][N] = A[M][K] * BT[N][K]^T   (bf16 in, OT out, fp32 accum)
// 128x128 tile per 256-thread block, BK=32, global_load_lds width-16 staging.
// ---------------------------------------------------------------------------
template <typename OT>
__global__ __launch_bounds__(256)
void gemm_bt_kernel(const __bf16* __restrict__ A, const __bf16* __restrict__ BT,
                    OT* __restrict__ C, int M, int N, int K)
{
    __shared__ __align__(16) __bf16 As[128 * 32];
    __shared__ __align__(16) __bf16 Bs[128 * 32];

    const int tid  = threadIdx.x;
    const int wave = tid >> 6;
    const int lane = tid & 63;
    const int quad = lane >> 4;
    const int l16  = lane & 15;

    const long m0 = (long)blockIdx.y * 128;
    const long n0 = (long)blockIdx.x * 128;
    const int  wm = (wave >> 1) * 64;
    const int  wn = (wave & 1) * 64;

    floatx4 acc[4][4] = {};

    for (int k0 = 0; k0 < K; k0 += 32) {
#pragma unroll
        for (int t = 0; t < 2; ++t) {
            const int c   = (t * 4 + wave) * 64 + lane;
            const int row = c >> 2;
            const int kc  = (c & 3) * 8;
            const __bf16* ga = A  + (m0 + row) * (long)K + k0 + kc;
            const __bf16* gb = BT + (n0 + row) * (long)K + k0 + kc;
            __builtin_amdgcn_global_load_lds(AS1(ga), AS3(As + (t * 4 + wave) * 512), 16, 0, 0);
            __builtin_amdgcn_global_load_lds(AS1(gb), AS3(Bs + (t * 4 + wave) * 512), 16, 0, 0);
        }
        asm volatile("s_waitcnt vmcnt(0)" ::: "memory");
        __syncthreads();

        bf16x8 af[4], bfq[4];
#pragma unroll
        for (int mt = 0; mt < 4; ++mt)
            af[mt] = *(const bf16x8*)(As + (wm + mt * 16 + l16) * 32 + quad * 8);
#pragma unroll
        for (int nt = 0; nt < 4; ++nt)
            bfq[nt] = *(const bf16x8*)(Bs + (wn + nt * 16 + l16) * 32 + quad * 8);

#pragma unroll
        for (int mt = 0; mt < 4; ++mt)
#pragma unroll
            for (int nt = 0; nt < 4; ++nt)
                acc[mt][nt] = __builtin_amdgcn_mfma_f32_16x16x32_bf16(
                    af[mt], bfq[nt], acc[mt][nt], 0, 0, 0);
        __syncthreads();
    }

#pragma unroll
    for (int mt = 0; mt < 4; ++mt)
#pragma unroll
        for (int nt = 0; nt < 4; ++nt) {
            const long row = m0 + wm + mt * 16 + quad * 4;
            const long col = n0 + wn + nt * 16 + l16;
#pragma unroll
            for (int r = 0; r < 4; ++r)
                C[(row + r) * (long)N + col] = (OT)acc[mt][nt][r];
        }
}

// ---------------------------------------------------------------------------
// RoPE + layout transform.
// QKV[8192][3072] -> Qr[bh][s][64], Kr[bh][s][64] (roped), Vt[bh][64][2048].
// ---------------------------------------------------------------------------
__global__ __launch_bounds__(256)
void rope_kernel(const __bf16* __restrict__ QKV,
                 __bf16* __restrict__ Qr, __bf16* __restrict__ Kr,
                 __bf16* __restrict__ Vt)
{
    const int bh = blockIdx.x;
    const int b  = bh >> 4, h = bh & 15;
    const int s  = blockIdx.y * 256 + threadIdx.x;

    const __bf16* base = QKV + ((size_t)(b * 2048 + s)) * 3072 + h * 64;

    float q[64], k[64];
#pragma unroll
    for (int d = 0; d < 64; ++d) {
        q[d] = (float)base[d];
        k[d] = (float)base[1024 + d];
    }

    __attribute__((aligned(16))) __bf16 qo[64];
    __attribute__((aligned(16))) __bf16 ko[64];

#pragma unroll
    for (int d = 0; d < 32; ++d) {
        const float f   = exp2f(-(float)d * 0.4152410118609203f);
        const float ang = (float)s * f;
        float sn, cs;
        sincosf(ang, &sn, &cs);
        qo[d]      = (__bf16)(q[d] * cs - q[d + 32] * sn);
        qo[d + 32] = (__bf16)(q[d + 32] * cs + q[d] * sn);
        ko[d]      = (__bf16)(k[d] * cs - k[d + 32] * sn);
        ko[d + 32] = (__bf16)(k[d + 32] * cs + k[d] * sn);
    }

    __bf16* qdst = Qr + ((size_t)bh * 2048 + s) * 64;
    __bf16* kdst = Kr + ((size_t)bh * 2048 + s) * 64;
#pragma unroll
    for (int i = 0; i < 8; ++i) {
        *(bf16x8*)(qdst + i * 8) = ((const bf16x8*)qo)[i];
        *(bf16x8*)(kdst + i * 8) = ((const bf16x8*)ko)[i];
    }
#pragma unroll
    for (int d = 0; d < 64; ++d)
        Vt[((size_t)bh * 64 + d) * 2048 + s] = base[2048 + d];
}

// ---------------------------------------------------------------------------
// Causal flash attention v3. grid = (32 paired q-chunks, 64 bh), block = 256.
// Q-chunks of 32 rows (64 per bh); waves {0,1} take chunk c, waves {2,3}
// take chunk 63-c -> uniform work per block, 2048 blocks = 8 blocks/CU =
// 32 waves/CU (full occupancy; VGPR<=64). S computed transposed (S^T=K*Q^T):
// softmax row = 8 in-lane regs + 2 cross-quad shfls; m,l scalar per lane.
// exp2-domain softmax (v_exp_f32 is natively 2^x).
// ---------------------------------------------------------------------------
__global__ __launch_bounds__(256, 8)
void attn_kernel(const __bf16* __restrict__ Qr, const __bf16* __restrict__ Kr,
                 const __bf16* __restrict__ Vt, __bf16* __restrict__ ctx)
{
    __shared__ __align__(16) __bf16 plds[4][16 * 40];   // wave-private P staging

    const int bh   = blockIdx.y;
    const int b    = bh >> 4, h = bh & 15;
    const int wave = threadIdx.x >> 6;
    const int lane = threadIdx.x & 63;
    const int quad = lane >> 4, l16 = lane & 15;

    const __bf16* Qb = Qr + (size_t)bh * 2048 * 64;
    const __bf16* Kb = Kr + (size_t)bh * 2048 * 64;
    const __bf16* Vb = Vt + (size_t)bh * 64 * 2048;
    __bf16* Pw = &plds[wave][0];

    // waves 0,1 -> chunk blockIdx.x; waves 2,3 -> chunk 63-blockIdx.x
    const int chunk = (wave < 2) ? (int)blockIdx.x : (63 - (int)blockIdx.x);
    const int q0 = chunk * 32 + (wave & 1) * 16;
    const int qa = q0 + l16;            // this lane's q-row (softmax domain)

    bf16x8 bq[2];
#pragma unroll
    for (int t = 0; t < 2; ++t)
        bq[t] = *(const bf16x8*)(Qb + (q0 + l16) * 64 + t * 32 + quad * 8);

    floatx4 o[4] = {};
    float m = MASKV, l = 0.f;

    const int kend = q0 + 16;           // keys 0 .. q0+15 inclusive

    // prefetch first K tile (A-frags: rows = keys)
    bf16x8 ka0[2], ka1[2];
#pragma unroll
    for (int t = 0; t < 2; ++t) {
        ka0[t] = *(const bf16x8*)(Kb + (l16)      * 64 + t * 32 + quad * 8);
        ka1[t] = *(const bf16x8*)(Kb + (16 + l16) * 64 + t * 32 + quad * 8);
    }

    for (int kt = 0; kt < kend; kt += 32) {
        // S^T tiles: D[key=quad*4+r][q=l16]
        floatx4 s0 = {}, s1 = {};
        s0 = __builtin_amdgcn_mfma_f32_16x16x32_bf16(ka0[0], bq[0], s0, 0, 0, 0);
        s0 = __builtin_amdgcn_mfma_f32_16x16x32_bf16(ka0[1], bq[1], s0, 0, 0, 0);
        s1 = __builtin_amdgcn_mfma_f32_16x16x32_bf16(ka1[0], bq[0], s1, 0, 0, 0);
        s1 = __builtin_amdgcn_mfma_f32_16x16x32_bf16(ka1[1], bq[1], s1, 0, 0, 0);

        // prefetch V for this tile (independent of softmax)
        bf16x8 bv[4];
#pragma unroll
        for (int nt = 0; nt < 4; ++nt)
            bv[nt] = *(const bf16x8*)(Vb + (nt * 16 + l16) * 2048 + kt + quad * 8);

        // prefetch next K tile
        if (kt + 32 < kend) {
#pragma unroll
            for (int t = 0; t < 2; ++t) {
                ka0[t] = *(const bf16x8*)(Kb + (kt + 32 + l16) * 64 + t * 32 + quad * 8);
                ka1[t] = *(const bf16x8*)(Kb + (kt + 48 + l16) * 64 + t * 32 + quad * 8);
            }
        }

        // mask + scale into log2 domain (key index = kt + quad*4 + r / +16)
        float v0[4], v1[4];
#pragma unroll
        for (int r = 0; r < 4; ++r) {
            v0[r] = (kt + quad * 4 + r      > qa) ? MASKV : s0[r] * SOFTMAX_SCALE_LOG2;
            v1[r] = (kt + 16 + quad * 4 + r > qa) ? MASKV : s1[r] * SOFTMAX_SCALE_LOG2;
        }

        // row max: 8 in-lane + 2 cross-quad shfls
        float mx = fmaxf(fmaxf(fmaxf(v0[0], v0[1]), fmaxf(v0[2], v0[3])),
                         fmaxf(fmaxf(v1[0], v1[1]), fmaxf(v1[2], v1[3])));
        mx = fmaxf(mx, __shfl_xor(mx, 16, 64));
        mx = fmaxf(mx, __shfl_xor(mx, 32, 64));
        const float mnew = fmaxf(m, mx);
        const float alpha = exp2f(m - mnew);   // first iter: 2^(-1e30)=0
        m = mnew;

        // broadcast alpha to O-layout rows early (latency hides under exps)
        float ar[4];
#pragma unroll
        for (int r = 0; r < 4; ++r)
            ar[r] = __shfl(alpha, quad * 4 + r, 64);

        float p0[4], p1[4], ps = 0.f;
#pragma unroll
        for (int r = 0; r < 4; ++r) {
            p0[r] = exp2f(v0[r] - mnew);
            p1[r] = exp2f(v1[r] - mnew);
            ps += p0[r] + p1[r];
        }
        ps += __shfl_xor(ps, 16, 64);
        ps += __shfl_xor(ps, 32, 64);
        l = l * alpha + ps;

        // store P in [q][key] rows: row l16, cols quad*4+r (+16)
        bf16x4 w0, w1;
#pragma unroll
        for (int r = 0; r < 4; ++r) { w0[r] = (__bf16)p0[r]; w1[r] = (__bf16)p1[r]; }
        *(bf16x4*)(Pw + l16 * 40 + quad * 4)      = w0;
        *(bf16x4*)(Pw + l16 * 40 + 16 + quad * 4) = w1;

        // rescale O rows (row q=quad*4+r)
#pragma unroll
        for (int nt = 0; nt < 4; ++nt)
#pragma unroll
            for (int r = 0; r < 4; ++r)
                o[nt][r] *= ar[r];

        asm volatile("s_waitcnt lgkmcnt(0)" ::: "memory");
        bf16x8 ap = *(const bf16x8*)(Pw + l16 * 40 + quad * 8);  // A[q][key]

#pragma unroll
        for (int nt = 0; nt < 4; ++nt)
            o[nt] = __builtin_amdgcn_mfma_f32_16x16x32_bf16(ap, bv[nt], o[nt], 0, 0, 0);
    }

    // epilogue: O row q=quad*4+r needs l from lane l16=quad*4+r
    float lr[4];
#pragma unroll
    for (int r = 0; r < 4; ++r)
        lr[r] = __shfl(l, quad * 4 + r, 64);
#pragma unroll
    for (int nt = 0; nt < 4; ++nt)
#pragma unroll
        for (int r = 0; r < 4; ++r) {
            const int s = q0 + quad * 4 + r;
            const float inv_l = 1.0f / fmaxf(lr[r], 1e-20f);
            ctx[((size_t)(b * 2048 + s)) * 1024 + h * 64 + nt * 16 + l16] =
                (__bf16)(o[nt][r] * inv_l);
        }
}

// ---------------------------------------------------------------------------
// Workspace layout (96 MiB):
//   [ 0M..48M)  QKV bf16 (dead after rope) -> ctx [0..16M), wob [16M..18M)
//   [48M..64M)  xb bf16 (dead after GEMM1) -> Qr
//   [64M..80M)  qkvb bf16 (dead after GEMM1) -> Kr
//   [80M..96M)  Vt bf16
// ---------------------------------------------------------------------------
extern "C" void kernel_launch(void* const* d_in, const int* in_sizes, int n_in,
                              void* d_out, int out_size, void* d_ws, size_t ws_size,
                              hipStream_t stream)
{
    const float* x   = (const float*)d_in[0];   // [4,2048,1024] fp32
    const float* qkv = (const float*)d_in[1];   // [3072,1024]   fp32 (N x K)
    const float* wo  = (const float*)d_in[2];   // [1024,1024]   fp32 (N x K)
    float* out = (float*)d_out;                 // [8192,1024]   fp32

    char* ws = (char*)d_ws;
    const size_t MB = 1024 * 1024;
    __bf16* QKV  = (__bf16*)(ws);
    __bf16* ctx  = (__bf16*)(ws);               // overlaps dead QKV
    __bf16* wob  = (__bf16*)(ws + 16 * MB);     // overlaps dead QKV
    __bf16* Qr   = (__bf16*)(ws + 48 * MB);
    __bf16* xb   = (__bf16*)(ws + 48 * MB);     // dead before Qr written
    __bf16* Kr   = (__bf16*)(ws + 64 * MB);
    __bf16* qkvb = (__bf16*)(ws + 64 * MB);     // dead before Kr written
    __bf16* Vt   = (__bf16*)(ws + 80 * MB);

    cvt_kernel<<<8192, 256, 0, stream>>>(x,   xb);
    cvt_kernel<<<3072, 256, 0, stream>>>(qkv, qkvb);
    gemm_bt_kernel<__bf16><<<dim3(24, 64), 256, 0, stream>>>(xb, qkvb, QKV, 8192, 3072, 1024);
    rope_kernel<<<dim3(64, 8), 256, 0, stream>>>(QKV, Qr, Kr, Vt);
    cvt_kernel<<<1024, 256, 0, stream>>>(wo, wob);
    attn_kernel<<<dim3(32, 64), 256, 0, stream>>>(Qr, Kr, Vt, ctx);
    gemm_bt_kernel<float><<<dim3(8, 64), 256, 0, stream>>>(ctx, wob, out, 8192, 1024, 1024);
}

// Round 6
// 460.123 us; speedup vs baseline: 1.9547x; 1.9547x over previous
//
#include <hip/hip_runtime.h>
#include <math.h>

typedef __bf16 bf16x8 __attribute__((ext_vector_type(8)));
typedef __bf16 bf16x4 __attribute__((ext_vector_type(4)));
typedef float  floatx4 __attribute__((ext_vector_type(4)));

#define AS1(p) ((__attribute__((address_space(1))) void*)(p))
#define AS3(p) ((__attribute__((address_space(3))) void*)(p))

#define MASKV (-1.0e30f)
#define SOFTMAX_SCALE_LOG2 0.1803368801111244f   // 0.125 * log2(e)

// ---------------------------------------------------------------------------
// fp32 -> bf16 conversion, 4 elems/thread, fully coalesced.
// ---------------------------------------------------------------------------
__global__ __launch_bounds__(256)
void cvt_kernel(const float* __restrict__ in, __bf16* __restrict__ out)
{
    const int i = (blockIdx.x * 256 + threadIdx.x) * 4;
    const floatx4 v = *(const floatx4*)(in + i);
    bf16x4 o;
    o[0] = (__bf16)v[0]; o[1] = (__bf16)v[1];
    o[2] = (__bf16)v[2]; o[3] = (__bf16)v[3];
    *(bf16x4*)(out + i) = o;
}

// ---------------------------------------------------------------------------
// C[M][N] = A[M][K] * BT[N][K]^T   (bf16 in, OT out, fp32 accum)
// 128x128 tile per 256-thread block, BK=32, global_load_lds width-16 staging.
// ---------------------------------------------------------------------------
template <typename OT>
__global__ __launch_bounds__(256)
void gemm_bt_kernel(const __bf16* __restrict__ A, const __bf16* __restrict__ BT,
                    OT* __restrict__ C, int M, int N, int K)
{
    __shared__ __align__(16) __bf16 As[128 * 32];
    __shared__ __align__(16) __bf16 Bs[128 * 32];

    const int tid  = threadIdx.x;
    const int wave = tid >> 6;
    const int lane = tid & 63;
    const int quad = lane >> 4;
    const int l16  = lane & 15;

    const long m0 = (long)blockIdx.y * 128;
    const long n0 = (long)blockIdx.x * 128;
    const int  wm = (wave >> 1) * 64;
    const int  wn = (wave & 1) * 64;

    floatx4 acc[4][4] = {};

    for (int k0 = 0; k0 < K; k0 += 32) {
#pragma unroll
        for (int t = 0; t < 2; ++t) {
            const int c   = (t * 4 + wave) * 64 + lane;
            const int row = c >> 2;
            const int kc  = (c & 3) * 8;
            const __bf16* ga = A  + (m0 + row) * (long)K + k0 + kc;
            const __bf16* gb = BT + (n0 + row) * (long)K + k0 + kc;
            __builtin_amdgcn_global_load_lds(AS1(ga), AS3(As + (t * 4 + wave) * 512), 16, 0, 0);
            __builtin_amdgcn_global_load_lds(AS1(gb), AS3(Bs + (t * 4 + wave) * 512), 16, 0, 0);
        }
        asm volatile("s_waitcnt vmcnt(0)" ::: "memory");
        __syncthreads();

        bf16x8 af[4], bfq[4];
#pragma unroll
        for (int mt = 0; mt < 4; ++mt)
            af[mt] = *(const bf16x8*)(As + (wm + mt * 16 + l16) * 32 + quad * 8);
#pragma unroll
        for (int nt = 0; nt < 4; ++nt)
            bfq[nt] = *(const bf16x8*)(Bs + (wn + nt * 16 + l16) * 32 + quad * 8);

#pragma unroll
        for (int mt = 0; mt < 4; ++mt)
#pragma unroll
            for (int nt = 0; nt < 4; ++nt)
                acc[mt][nt] = __builtin_amdgcn_mfma_f32_16x16x32_bf16(
                    af[mt], bfq[nt], acc[mt][nt], 0, 0, 0);
        __syncthreads();
    }

#pragma unroll
    for (int mt = 0; mt < 4; ++mt)
#pragma unroll
        for (int nt = 0; nt < 4; ++nt) {
            const long row = m0 + wm + mt * 16 + quad * 4;
            const long col = n0 + wn + nt * 16 + l16;
#pragma unroll
            for (int r = 0; r < 4; ++r)
                C[(row + r) * (long)N + col] = (OT)acc[mt][nt][r];
        }
}

// ---------------------------------------------------------------------------
// RoPE + layout transform.
// QKV[8192][3072] -> Qr[bh][s][64], Kr[bh][s][64] (roped), Vt[bh][64][2048].
// ---------------------------------------------------------------------------
__global__ __launch_bounds__(256)
void rope_kernel(const __bf16* __restrict__ QKV,
                 __bf16* __restrict__ Qr, __bf16* __restrict__ Kr,
                 __bf16* __restrict__ Vt)
{
    const int bh = blockIdx.x;
    const int b  = bh >> 4, h = bh & 15;
    const int s  = blockIdx.y * 256 + threadIdx.x;

    const __bf16* base = QKV + ((size_t)(b * 2048 + s)) * 3072 + h * 64;

    float q[64], k[64];
#pragma unroll
    for (int d = 0; d < 64; ++d) {
        q[d] = (float)base[d];
        k[d] = (float)base[1024 + d];
    }

    __attribute__((aligned(16))) __bf16 qo[64];
    __attribute__((aligned(16))) __bf16 ko[64];

#pragma unroll
    for (int d = 0; d < 32; ++d) {
        const float f   = exp2f(-(float)d * 0.4152410118609203f);
        const float ang = (float)s * f;
        float sn, cs;
        sincosf(ang, &sn, &cs);
        qo[d]      = (__bf16)(q[d] * cs - q[d + 32] * sn);
        qo[d + 32] = (__bf16)(q[d + 32] * cs + q[d] * sn);
        ko[d]      = (__bf16)(k[d] * cs - k[d + 32] * sn);
        ko[d + 32] = (__bf16)(k[d + 32] * cs + k[d] * sn);
    }

    __bf16* qdst = Qr + ((size_t)bh * 2048 + s) * 64;
    __bf16* kdst = Kr + ((size_t)bh * 2048 + s) * 64;
#pragma unroll
    for (int i = 0; i < 8; ++i) {
        *(bf16x8*)(qdst + i * 8) = ((const bf16x8*)qo)[i];
        *(bf16x8*)(kdst + i * 8) = ((const bf16x8*)ko)[i];
    }
#pragma unroll
    for (int d = 0; d < 64; ++d)
        Vt[((size_t)bh * 64 + d) * 2048 + s] = base[2048 + d];
}

// ---------------------------------------------------------------------------
// Causal flash attention v3b. grid = (32 paired q-chunks, 64 bh), block=256.
// Q-chunks of 32 rows (64 per bh); waves {0,1} take chunk c, waves {2,3}
// take chunk 63-c -> uniform work per block; 2048 blocks allows 8 blocks/CU.
// __launch_bounds__(256,4): VGPR cap 128 -> compiler lands ~56 (no spills;
// round 5's (256,8) forced VGPR=32 and spilled 2+ GB to scratch).
// HW still reaches 8 waves/SIMD since 56 <= 64 VGPRs.
// S computed transposed (S^T=K*Q^T): softmax row = 8 in-lane regs + 2
// cross-quad shfls; m,l scalar per lane; exp2-domain softmax.
// ---------------------------------------------------------------------------
__global__ __launch_bounds__(256, 4)
void attn_kernel(const __bf16* __restrict__ Qr, const __bf16* __restrict__ Kr,
                 const __bf16* __restrict__ Vt, __bf16* __restrict__ ctx)
{
    __shared__ __align__(16) __bf16 plds[4][16 * 40];   // wave-private P staging

    const int bh   = blockIdx.y;
    const int b    = bh >> 4, h = bh & 15;
    const int wave = threadIdx.x >> 6;
    const int lane = threadIdx.x & 63;
    const int quad = lane >> 4, l16 = lane & 15;

    const __bf16* Qb = Qr + (size_t)bh * 2048 * 64;
    const __bf16* Kb = Kr + (size_t)bh * 2048 * 64;
    const __bf16* Vb = Vt + (size_t)bh * 64 * 2048;
    __bf16* Pw = &plds[wave][0];

    // waves 0,1 -> chunk blockIdx.x; waves 2,3 -> chunk 63-blockIdx.x
    const int chunk = (wave < 2) ? (int)blockIdx.x : (63 - (int)blockIdx.x);
    const int q0 = chunk * 32 + (wave & 1) * 16;
    const int qa = q0 + l16;            // this lane's q-row (softmax domain)

    bf16x8 bq[2];
#pragma unroll
    for (int t = 0; t < 2; ++t)
        bq[t] = *(const bf16x8*)(Qb + (q0 + l16) * 64 + t * 32 + quad * 8);

    floatx4 o[4] = {};
    float m = MASKV, l = 0.f;

    const int kend = q0 + 16;           // keys 0 .. q0+15 inclusive

    // prefetch first K tile (A-frags: rows = keys)
    bf16x8 ka0[2], ka1[2];
#pragma unroll
    for (int t = 0; t < 2; ++t) {
        ka0[t] = *(const bf16x8*)(Kb + (l16)      * 64 + t * 32 + quad * 8);
        ka1[t] = *(const bf16x8*)(Kb + (16 + l16) * 64 + t * 32 + quad * 8);
    }

    for (int kt = 0; kt < kend; kt += 32) {
        // S^T tiles: D[key=quad*4+r][q=l16]
        floatx4 s0 = {}, s1 = {};
        s0 = __builtin_amdgcn_mfma_f32_16x16x32_bf16(ka0[0], bq[0], s0, 0, 0, 0);
        s0 = __builtin_amdgcn_mfma_f32_16x16x32_bf16(ka0[1], bq[1], s0, 0, 0, 0);
        s1 = __builtin_amdgcn_mfma_f32_16x16x32_bf16(ka1[0], bq[0], s1, 0, 0, 0);
        s1 = __builtin_amdgcn_mfma_f32_16x16x32_bf16(ka1[1], bq[1], s1, 0, 0, 0);

        // prefetch V for this tile (independent of softmax)
        bf16x8 bv[4];
#pragma unroll
        for (int nt = 0; nt < 4; ++nt)
            bv[nt] = *(const bf16x8*)(Vb + (nt * 16 + l16) * 2048 + kt + quad * 8);

        // prefetch next K tile
        if (kt + 32 < kend) {
#pragma unroll
            for (int t = 0; t < 2; ++t) {
                ka0[t] = *(const bf16x8*)(Kb + (kt + 32 + l16) * 64 + t * 32 + quad * 8);
                ka1[t] = *(const bf16x8*)(Kb + (kt + 48 + l16) * 64 + t * 32 + quad * 8);
            }
        }

        // mask + scale into log2 domain (key index = kt + quad*4 + r / +16)
        float v0[4], v1[4];
#pragma unroll
        for (int r = 0; r < 4; ++r) {
            v0[r] = (kt + quad * 4 + r      > qa) ? MASKV : s0[r] * SOFTMAX_SCALE_LOG2;
            v1[r] = (kt + 16 + quad * 4 + r > qa) ? MASKV : s1[r] * SOFTMAX_SCALE_LOG2;
        }

        // row max: 8 in-lane + 2 cross-quad shfls
        float mx = fmaxf(fmaxf(fmaxf(v0[0], v0[1]), fmaxf(v0[2], v0[3])),
                         fmaxf(fmaxf(v1[0], v1[1]), fmaxf(v1[2], v1[3])));
        mx = fmaxf(mx, __shfl_xor(mx, 16, 64));
        mx = fmaxf(mx, __shfl_xor(mx, 32, 64));
        const float mnew = fmaxf(m, mx);
        const float alpha = exp2f(m - mnew);   // first iter: 2^(-1e30)=0
        m = mnew;

        // broadcast alpha to O-layout rows early (latency hides under exps)
        float ar[4];
#pragma unroll
        for (int r = 0; r < 4; ++r)
            ar[r] = __shfl(alpha, quad * 4 + r, 64);

        float p0[4], p1[4], ps = 0.f;
#pragma unroll
        for (int r = 0; r < 4; ++r) {
            p0[r] = exp2f(v0[r] - mnew);
            p1[r] = exp2f(v1[r] - mnew);
            ps += p0[r] + p1[r];
        }
        ps += __shfl_xor(ps, 16, 64);
        ps += __shfl_xor(ps, 32, 64);
        l = l * alpha + ps;

        // store P in [q][key] rows: row l16, cols quad*4+r (+16)
        bf16x4 w0, w1;
#pragma unroll
        for (int r = 0; r < 4; ++r) { w0[r] = (__bf16)p0[r]; w1[r] = (__bf16)p1[r]; }
        *(bf16x4*)(Pw + l16 * 40 + quad * 4)      = w0;
        *(bf16x4*)(Pw + l16 * 40 + 16 + quad * 4) = w1;

        // rescale O rows (row q=quad*4+r)
#pragma unroll
        for (int nt = 0; nt < 4; ++nt)
#pragma unroll
            for (int r = 0; r < 4; ++r)
                o[nt][r] *= ar[r];

        asm volatile("s_waitcnt lgkmcnt(0)" ::: "memory");
        bf16x8 ap = *(const bf16x8*)(Pw + l16 * 40 + quad * 8);  // A[q][key]

#pragma unroll
        for (int nt = 0; nt < 4; ++nt)
            o[nt] = __builtin_amdgcn_mfma_f32_16x16x32_bf16(ap, bv[nt], o[nt], 0, 0, 0);
    }

    // epilogue: O row q=quad*4+r needs l from lane l16=quad*4+r
    float lr[4];
#pragma unroll
    for (int r = 0; r < 4; ++r)
        lr[r] = __shfl(l, quad * 4 + r, 64);
#pragma unroll
    for (int nt = 0; nt < 4; ++nt)
#pragma unroll
        for (int r = 0; r < 4; ++r) {
            const int s = q0 + quad * 4 + r;
            const float inv_l = 1.0f / fmaxf(lr[r], 1e-20f);
            ctx[((size_t)(b * 2048 + s)) * 1024 + h * 64 + nt * 16 + l16] =
                (__bf16)(o[nt][r] * inv_l);
        }
}

// ---------------------------------------------------------------------------
// Workspace layout (96 MiB):
//   [ 0M..48M)  QKV bf16 (dead after rope) -> ctx [0..16M), wob [16M..18M)
//   [48M..64M)  xb bf16 (dead after GEMM1) -> Qr
//   [64M..80M)  qkvb bf16 (dead after GEMM1) -> Kr
//   [80M..96M)  Vt bf16
// ---------------------------------------------------------------------------
extern "C" void kernel_launch(void* const* d_in, const int* in_sizes, int n_in,
                              void* d_out, int out_size, void* d_ws, size_t ws_size,
                              hipStream_t stream)
{
    const float* x   = (const float*)d_in[0];   // [4,2048,1024] fp32
    const float* qkv = (const float*)d_in[1];   // [3072,1024]   fp32 (N x K)
    const float* wo  = (const float*)d_in[2];   // [1024,1024]   fp32 (N x K)
    float* out = (float*)d_out;                 // [8192,1024]   fp32

    char* ws = (char*)d_ws;
    const size_t MB = 1024 * 1024;
    __bf16* QKV  = (__bf16*)(ws);
    __bf16* ctx  = (__bf16*)(ws);               // overlaps dead QKV
    __bf16* wob  = (__bf16*)(ws + 16 * MB);     // overlaps dead QKV
    __bf16* Qr   = (__bf16*)(ws + 48 * MB);
    __bf16* xb   = (__bf16*)(ws + 48 * MB);     // dead before Qr written
    __bf16* Kr   = (__bf16*)(ws + 64 * MB);
    __bf16* qkvb = (__bf16*)(ws + 64 * MB);     // dead before Kr written
    __bf16* Vt   = (__bf16*)(ws + 80 * MB);

    cvt_kernel<<<8192, 256, 0, stream>>>(x,   xb);
    cvt_kernel<<<3072, 256, 0, stream>>>(qkv, qkvb);
    gemm_bt_kernel<__bf16><<<dim3(24, 64), 256, 0, stream>>>(xb, qkvb, QKV, 8192, 3072, 1024);
    rope_kernel<<<dim3(64, 8), 256, 0, stream>>>(QKV, Qr, Kr, Vt);
    cvt_kernel<<<1024, 256, 0, stream>>>(wo, wob);
    attn_kernel<<<dim3(32, 64), 256, 0, stream>>>(Qr, Kr, Vt, ctx);
    gemm_bt_kernel<float><<<dim3(8, 64), 256, 0, stream>>>(ctx, wob, out, 8192, 1024, 1024);
}

// Round 7
// 457.535 us; speedup vs baseline: 1.9658x; 1.0057x over previous
//
#include <hip/hip_runtime.h>
#include <math.h>

typedef __bf16 bf16x8 __attribute__((ext_vector_type(8)));
typedef __bf16 bf16x4 __attribute__((ext_vector_type(4)));
typedef float  floatx4 __attribute__((ext_vector_type(4)));

#define AS1(p) ((__attribute__((address_space(1))) void*)(p))
#define AS3(p) ((__attribute__((address_space(3))) void*)(p))

#define MASKV (-1.0e30f)
#define SOFTMAX_SCALE_LOG2 0.1803368801111244f   // 0.125 * log2(e)

// ---------------------------------------------------------------------------
// fp32 -> bf16 conversion, 4 elems/thread, fully coalesced.
// ---------------------------------------------------------------------------
__global__ __launch_bounds__(256)
void cvt_kernel(const float* __restrict__ in, __bf16* __restrict__ out)
{
    const int i = (blockIdx.x * 256 + threadIdx.x) * 4;
    const floatx4 v = *(const floatx4*)(in + i);
    bf16x4 o;
    o[0] = (__bf16)v[0]; o[1] = (__bf16)v[1];
    o[2] = (__bf16)v[2]; o[3] = (__bf16)v[3];
    *(bf16x4*)(out + i) = o;
}

// ---------------------------------------------------------------------------
// C[M][N] = A[M][K] * BT[N][K]^T   (bf16 in, OT out, fp32 accum)
// 128x128 tile per 256-thread block, BK=32, global_load_lds width-16 staging.
// ---------------------------------------------------------------------------
template <typename OT>
__global__ __launch_bounds__(256)
void gemm_bt_kernel(const __bf16* __restrict__ A, const __bf16* __restrict__ BT,
                    OT* __restrict__ C, int M, int N, int K)
{
    __shared__ __align__(16) __bf16 As[128 * 32];
    __shared__ __align__(16) __bf16 Bs[128 * 32];

    const int tid  = threadIdx.x;
    const int wave = tid >> 6;
    const int lane = tid & 63;
    const int quad = lane >> 4;
    const int l16  = lane & 15;

    const long m0 = (long)blockIdx.y * 128;
    const long n0 = (long)blockIdx.x * 128;
    const int  wm = (wave >> 1) * 64;
    const int  wn = (wave & 1) * 64;

    floatx4 acc[4][4] = {};

    for (int k0 = 0; k0 < K; k0 += 32) {
#pragma unroll
        for (int t = 0; t < 2; ++t) {
            const int c   = (t * 4 + wave) * 64 + lane;
            const int row = c >> 2;
            const int kc  = (c & 3) * 8;
            const __bf16* ga = A  + (m0 + row) * (long)K + k0 + kc;
            const __bf16* gb = BT + (n0 + row) * (long)K + k0 + kc;
            __builtin_amdgcn_global_load_lds(AS1(ga), AS3(As + (t * 4 + wave) * 512), 16, 0, 0);
            __builtin_amdgcn_global_load_lds(AS1(gb), AS3(Bs + (t * 4 + wave) * 512), 16, 0, 0);
        }
        asm volatile("s_waitcnt vmcnt(0)" ::: "memory");
        __syncthreads();

        bf16x8 af[4], bfq[4];
#pragma unroll
        for (int mt = 0; mt < 4; ++mt)
            af[mt] = *(const bf16x8*)(As + (wm + mt * 16 + l16) * 32 + quad * 8);
#pragma unroll
        for (int nt = 0; nt < 4; ++nt)
            bfq[nt] = *(const bf16x8*)(Bs + (wn + nt * 16 + l16) * 32 + quad * 8);

#pragma unroll
        for (int mt = 0; mt < 4; ++mt)
#pragma unroll
            for (int nt = 0; nt < 4; ++nt)
                acc[mt][nt] = __builtin_amdgcn_mfma_f32_16x16x32_bf16(
                    af[mt], bfq[nt], acc[mt][nt], 0, 0, 0);
        __syncthreads();
    }

#pragma unroll
    for (int mt = 0; mt < 4; ++mt)
#pragma unroll
        for (int nt = 0; nt < 4; ++nt) {
            const long row = m0 + wm + mt * 16 + quad * 4;
            const long col = n0 + wn + nt * 16 + l16;
#pragma unroll
            for (int r = 0; r < 4; ++r)
                C[(row + r) * (long)N + col] = (OT)acc[mt][nt][r];
        }
}

// ---------------------------------------------------------------------------
// RoPE + layout transform.
// QKV[8192][3072] -> Qr[bh][s][64], Kr[bh][s][64] (roped), Vt[bh][64][2048].
// ---------------------------------------------------------------------------
__global__ __launch_bounds__(256)
void rope_kernel(const __bf16* __restrict__ QKV,
                 __bf16* __restrict__ Qr, __bf16* __restrict__ Kr,
                 __bf16* __restrict__ Vt)
{
    const int bh = blockIdx.x;
    const int b  = bh >> 4, h = bh & 15;
    const int s  = blockIdx.y * 256 + threadIdx.x;

    const __bf16* base = QKV + ((size_t)(b * 2048 + s)) * 3072 + h * 64;

    float q[64], k[64];
#pragma unroll
    for (int d = 0; d < 64; ++d) {
        q[d] = (float)base[d];
        k[d] = (float)base[1024 + d];
    }

    __attribute__((aligned(16))) __bf16 qo[64];
    __attribute__((aligned(16))) __bf16 ko[64];

#pragma unroll
    for (int d = 0; d < 32; ++d) {
        const float f   = exp2f(-(float)d * 0.4152410118609203f);
        const float ang = (float)s * f;
        float sn, cs;
        sincosf(ang, &sn, &cs);
        qo[d]      = (__bf16)(q[d] * cs - q[d + 32] * sn);
        qo[d + 32] = (__bf16)(q[d + 32] * cs + q[d] * sn);
        ko[d]      = (__bf16)(k[d] * cs - k[d + 32] * sn);
        ko[d + 32] = (__bf16)(k[d + 32] * cs + k[d] * sn);
    }

    __bf16* qdst = Qr + ((size_t)bh * 2048 + s) * 64;
    __bf16* kdst = Kr + ((size_t)bh * 2048 + s) * 64;
#pragma unroll
    for (int i = 0; i < 8; ++i) {
        *(bf16x8*)(qdst + i * 8) = ((const bf16x8*)qo)[i];
        *(bf16x8*)(kdst + i * 8) = ((const bf16x8*)ko)[i];
    }
#pragma unroll
    for (int d = 0; d < 64; ++d)
        Vt[((size_t)bh * 64 + d) * 2048 + s] = base[2048 + d];
}

// ---------------------------------------------------------------------------
// Causal flash attention v4. grid = (8, 64 bh), block = 256 (4 waves).
// Wave w_g = blockIdx.x*4 + wave (0..31) sequentially owns 4 q-tiles of 16
// rows: {w_g, 63-w_g, 64+w_g, 127-w_g} -> ~64.5 K-iters per wave, uniform.
// 512 blocks = 2 blocks/CU, all resident, zero tail.
// K-tile = 64: ONE softmax reduction + ONE LDS round-trip per 64 keys.
// K and V fragments register-prefetched: reloaded immediately after their
// MFMA consumption so next iter's loads fly during this iter's softmax.
// S computed transposed (S^T = K*Q^T): softmax row in-lane (16 vals) + 2
// cross-quad shfls; m,l scalar per lane; exp2-domain.
// __launch_bounds__(256,3): VGPR cap ~170, live set ~140 -> no spills.
// ---------------------------------------------------------------------------
__global__ __launch_bounds__(256, 3)
void attn_kernel(const __bf16* __restrict__ Qr, const __bf16* __restrict__ Kr,
                 const __bf16* __restrict__ Vt, __bf16* __restrict__ ctx)
{
    __shared__ __align__(16) __bf16 plds[4][16 * 72];   // wave-private P staging

    const int bh   = blockIdx.y;
    const int b    = bh >> 4, h = bh & 15;
    const int wave = threadIdx.x >> 6;
    const int lane = threadIdx.x & 63;
    const int quad = lane >> 4, l16 = lane & 15;

    const __bf16* Qb = Qr + (size_t)bh * 2048 * 64;
    const __bf16* Kb = Kr + (size_t)bh * 2048 * 64;
    const __bf16* Vb = Vt + (size_t)bh * 64 * 2048;
    __bf16* Pw = &plds[wave][0];

    const int w_g = (int)blockIdx.x * 4 + wave;   // 0..31
    const int tiles[4] = { w_g, 63 - w_g, 64 + w_g, 127 - w_g };

    for (int pass = 0; pass < 4; ++pass) {
        const int q0 = tiles[pass] * 16;
        const int qa = q0 + l16;                  // this lane's q-row
        const int kend = q0 + 16;                 // keys 0 .. q0+15

        bf16x8 bq[2];
#pragma unroll
        for (int t = 0; t < 2; ++t)
            bq[t] = *(const bf16x8*)(Qb + (q0 + l16) * 64 + t * 32 + quad * 8);

        floatx4 o[4] = {};
        float m = MASKV, l = 0.f;

        // preload K tile 0 (A-frags, rows = keys) and V tile 0 (B-frags)
        bf16x8 ka[4][2], bv[4][2];
#pragma unroll
        for (int st = 0; st < 4; ++st)
#pragma unroll
            for (int t = 0; t < 2; ++t)
                ka[st][t] = *(const bf16x8*)(Kb + (st * 16 + l16) * 64 + t * 32 + quad * 8);
#pragma unroll
        for (int nt = 0; nt < 4; ++nt)
#pragma unroll
            for (int hf = 0; hf < 2; ++hf)
                bv[nt][hf] = *(const bf16x8*)(Vb + (nt * 16 + l16) * 2048 + hf * 32 + quad * 8);

        for (int kt = 0; kt < kend; kt += 64) {
            const bool next = (kt + 64 < kend);

            // S^T: D[key = st*16 + quad*4 + r][q = l16]
            floatx4 s[4] = {};
#pragma unroll
            for (int st = 0; st < 4; ++st) {
                s[st] = __builtin_amdgcn_mfma_f32_16x16x32_bf16(ka[st][0], bq[0], s[st], 0, 0, 0);
                s[st] = __builtin_amdgcn_mfma_f32_16x16x32_bf16(ka[st][1], bq[1], s[st], 0, 0, 0);
            }

            // prefetch next K tile (ka consumed above; loads fly over softmax)
            if (next) {
#pragma unroll
                for (int st = 0; st < 4; ++st)
#pragma unroll
                    for (int t = 0; t < 2; ++t)
                        ka[st][t] = *(const bf16x8*)(Kb + (kt + 64 + st * 16 + l16) * 64 + t * 32 + quad * 8);
            }

            // mask + scale into log2 domain; 16 in-lane values cover 64 keys
            float v[4][4];
#pragma unroll
            for (int st = 0; st < 4; ++st)
#pragma unroll
                for (int r = 0; r < 4; ++r) {
                    const int key = kt + st * 16 + quad * 4 + r;
                    v[st][r] = (key > qa) ? MASKV : s[st][r] * SOFTMAX_SCALE_LOG2;
                }

            // row max: 15 in-lane + 2 cross-quad shfls
            float mx = v[0][0];
#pragma unroll
            for (int st = 0; st < 4; ++st)
#pragma unroll
                for (int r = 0; r < 4; ++r)
                    mx = fmaxf(mx, v[st][r]);
            mx = fmaxf(mx, __shfl_xor(mx, 16, 64));
            mx = fmaxf(mx, __shfl_xor(mx, 32, 64));
            const float mnew = fmaxf(m, mx);
            const float alpha = exp2f(m - mnew);   // first iter: 2^(-1e30)=0
            m = mnew;

            // broadcast alpha to O-layout rows early (hides under exps)
            float ar[4];
#pragma unroll
            for (int r = 0; r < 4; ++r)
                ar[r] = __shfl(alpha, quad * 4 + r, 64);

            float ps = 0.f;
            float p[4][4];
#pragma unroll
            for (int st = 0; st < 4; ++st)
#pragma unroll
                for (int r = 0; r < 4; ++r) {
                    p[st][r] = exp2f(v[st][r] - mnew);
                    ps += p[st][r];
                }
            ps += __shfl_xor(ps, 16, 64);
            ps += __shfl_xor(ps, 32, 64);
            l = l * alpha + ps;

            // store P rows [q=l16][key col]: 4x ds_write_b64
#pragma unroll
            for (int st = 0; st < 4; ++st) {
                bf16x4 w;
#pragma unroll
                for (int r = 0; r < 4; ++r) w[r] = (__bf16)p[st][r];
                *(bf16x4*)(Pw + l16 * 72 + st * 16 + quad * 4) = w;
            }

            // rescale O rows (row q = quad*4+r)
#pragma unroll
            for (int nt = 0; nt < 4; ++nt)
#pragma unroll
                for (int r = 0; r < 4; ++r)
                    o[nt][r] *= ar[r];

            asm volatile("s_waitcnt lgkmcnt(0)" ::: "memory");
            bf16x8 ap0 = *(const bf16x8*)(Pw + l16 * 72 + quad * 8);
            bf16x8 ap1 = *(const bf16x8*)(Pw + l16 * 72 + 32 + quad * 8);

#pragma unroll
            for (int nt = 0; nt < 4; ++nt)
                o[nt] = __builtin_amdgcn_mfma_f32_16x16x32_bf16(ap0, bv[nt][0], o[nt], 0, 0, 0);
#pragma unroll
            for (int nt = 0; nt < 4; ++nt)
                o[nt] = __builtin_amdgcn_mfma_f32_16x16x32_bf16(ap1, bv[nt][1], o[nt], 0, 0, 0);

            // prefetch next V tile (bv consumed above)
            if (next) {
#pragma unroll
                for (int nt = 0; nt < 4; ++nt)
#pragma unroll
                    for (int hf = 0; hf < 2; ++hf)
                        bv[nt][hf] = *(const bf16x8*)(Vb + (nt * 16 + l16) * 2048 + kt + 64 + hf * 32 + quad * 8);
            }
        }

        // epilogue: O row q=quad*4+r needs l from lane quad*4+r (l uniform
        // across quads for fixed l16)
        float lr[4];
#pragma unroll
        for (int r = 0; r < 4; ++r)
            lr[r] = __shfl(l, quad * 4 + r, 64);
#pragma unroll
        for (int nt = 0; nt < 4; ++nt)
#pragma unroll
            for (int r = 0; r < 4; ++r) {
                const int srow = q0 + quad * 4 + r;
                const float inv_l = 1.0f / fmaxf(lr[r], 1e-20f);
                ctx[((size_t)(b * 2048 + srow)) * 1024 + h * 64 + nt * 16 + l16] =
                    (__bf16)(o[nt][r] * inv_l);
            }
    }
}

// ---------------------------------------------------------------------------
// Workspace layout (96 MiB):
//   [ 0M..48M)  QKV bf16 (dead after rope) -> ctx [0..16M), wob [16M..18M)
//   [48M..64M)  xb bf16 (dead after GEMM1) -> Qr
//   [64M..80M)  qkvb bf16 (dead after GEMM1) -> Kr
//   [80M..96M)  Vt bf16
// ---------------------------------------------------------------------------
extern "C" void kernel_launch(void* const* d_in, const int* in_sizes, int n_in,
                              void* d_out, int out_size, void* d_ws, size_t ws_size,
                              hipStream_t stream)
{
    const float* x   = (const float*)d_in[0];   // [4,2048,1024] fp32
    const float* qkv = (const float*)d_in[1];   // [3072,1024]   fp32 (N x K)
    const float* wo  = (const float*)d_in[2];   // [1024,1024]   fp32 (N x K)
    float* out = (float*)d_out;                 // [8192,1024]   fp32

    char* ws = (char*)d_ws;
    const size_t MB = 1024 * 1024;
    __bf16* QKV  = (__bf16*)(ws);
    __bf16* ctx  = (__bf16*)(ws);               // overlaps dead QKV
    __bf16* wob  = (__bf16*)(ws + 16 * MB);     // overlaps dead QKV
    __bf16* Qr   = (__bf16*)(ws + 48 * MB);
    __bf16* xb   = (__bf16*)(ws + 48 * MB);     // dead before Qr written
    __bf16* Kr   = (__bf16*)(ws + 64 * MB);
    __bf16* qkvb = (__bf16*)(ws + 64 * MB);     // dead before Kr written
    __bf16* Vt   = (__bf16*)(ws + 80 * MB);

    cvt_kernel<<<8192, 256, 0, stream>>>(x,   xb);
    cvt_kernel<<<3072, 256, 0, stream>>>(qkv, qkvb);
    gemm_bt_kernel<__bf16><<<dim3(24, 64), 256, 0, stream>>>(xb, qkvb, QKV, 8192, 3072, 1024);
    rope_kernel<<<dim3(64, 8), 256, 0, stream>>>(QKV, Qr, Kr, Vt);
    cvt_kernel<<<1024, 256, 0, stream>>>(wo, wob);
    attn_kernel<<<dim3(8, 64), 256, 0, stream>>>(Qr, Kr, Vt, ctx);
    gemm_bt_kernel<float><<<dim3(8, 64), 256, 0, stream>>>(ctx, wob, out, 8192, 1024, 1024);
}